// Round 5
// baseline (614.823 us; speedup 1.0000x reference)
//
#include <hip/hip_runtime.h>
#include <stdint.h>

// ---------------------------------------------------------------------------
// R5: 5-dispatch pipeline, 478 MB total traffic.
//  prep_hist: weight transposes (f32+f16), LUT, per-block/per-subchunk input
//             histograms (layer-0 carries are closed-form from histograms).
//  midA: LUT layer0 (LDS) + dense1 (MFMA f16) + scan -> Y1 (only Y write).
//  midB: Y1 -> dense2 -> Y2 (in-place).
//  midC: Y2 -> dense3 -> scan -> final dense (Wf*local) -> out_partial.
//  fixk: out += INVN * Wf*carry3 (per 64-chunk constant).
//  Carries: each kernel publishes per-block totals T + per-64-chunk aggs A64;
//  the NEXT kernel's blocks compute their own prefix (<=255 L2 rows) in the
//  prologue, overlapped with other setup. No scanA dispatches.
//  Y holds per-64-chunk-local flattened cumsum (same magnitudes as R4 ->
//  f16 rounding unchanged, absmax ~1.5e-8).
// ---------------------------------------------------------------------------

#define BB 4
#define SP 65536
#define SS 196608
#define INVN (1.0f / 196608.0f)

typedef __attribute__((ext_vector_type(8))) _Float16 half8;
typedef __attribute__((ext_vector_type(4))) float    f32x4;

// ---------------- prep + histograms -----------------------------------------
__global__ __launch_bounds__(256)
void prep_hist(const int* __restrict__ ex, const float* __restrict__ W0,
               const float* __restrict__ b0, const float* __restrict__ Wr,
               const float* __restrict__ Wfin,
               float* __restrict__ Wt32, _Float16* __restrict__ Wt16,
               _Float16* __restrict__ Wf16, _Float16* __restrict__ tab16,
               int* __restrict__ Hsub, int* __restrict__ HT)
{
    __shared__ int hist[4][24];
    int tid = threadIdx.x, bi = blockIdx.x;
    int b = bi >> 8, g = bi & 255;
    if (tid < 96) hist[tid / 24][tid % 24] = 0;
    __syncthreads();
    {
        const int* ep = ex + ((size_t)b * SP + g * 256 + tid) * 3;
        int it = tid >> 6;
        atomicAdd(&hist[it][ep[0]], 1);
        atomicAdd(&hist[it][8 + ep[1]], 1);
        atomicAdd(&hist[it][16 + ep[2]], 1);
    }
    if (bi < 64) {
        int i = bi * 256 + tid, nth = 64 * 256;
        for (int idx = i; idx < 36864; idx += nth) {   // Wt[l][c][f][d]
            int d = idx & 63, f = (idx >> 6) & 63, lc = idx >> 12;
            float v = Wr[(size_t)(lc * 64 + d) * 64 + f];
            Wt32[idx] = v; Wt16[idx] = (_Float16)v;
        }
        for (int idx = i; idx < 1536; idx += nth) {    // Wf[c][k][d]
            int d = idx & 63, k = (idx >> 6) & 7, c = idx >> 9;
            Wf16[idx] = (_Float16)Wfin[(size_t)(c * 64 + d) * 8 + k];
        }
        for (int idx = i; idx < 1536; idx += nth) {    // tab[c][v][f]
            int f = idx & 63, v = (idx >> 6) & 7, c = idx >> 9;
            float xv = v * 0.25f - 1.0f;
            tab16[idx] = (_Float16)fmaxf(W0[c * 64 + f] * xv + b0[c * 64 + f], 0.f);
        }
    }
    __syncthreads();
    if (tid < 96) Hsub[((bi << 2) | (tid / 24)) * 24 + tid % 24] = hist[tid / 24][tid % 24];
    if (tid < 24) HT[bi * 32 + tid] = hist[0][tid] + hist[1][tid] + hist[2][tid] + hist[3][tid];
}

// ---------------- midA: LUT layer0 + dense1 -> Y1 ---------------------------
__global__ __launch_bounds__(256, 4)
void midA(const int* __restrict__ ex,
          const int* __restrict__ Hsub, const int* __restrict__ HT,
          const _Float16* __restrict__ tab16,
          const _Float16* __restrict__ W16, const float* __restrict__ W32,
          const float* __restrict__ bias,
          _Float16* __restrict__ Y, float* __restrict__ A64, float* __restrict__ T)
{
    __shared__ _Float16 stab[1536];
    __shared__ __align__(16) _Float16 bounce3[3][64 * 72];
    __shared__ float segwt[3][4][64];
    __shared__ float basearr4[4][192];
    __shared__ float phist[8][24];
    __shared__ float h3[3][24];
    __shared__ float scnt4[4][24];
    __shared__ __align__(16) float scarr4[4][64];

    int tid = threadIdx.x, bi = blockIdx.x;
    int b = bi >> 8, g = bi & 255;
    int w = tid >> 6, ln = tid & 63, lm = ln & 15, lq = ln >> 4;
    int f = ln;

    for (int i = tid; i < 1536; i += 256) stab[i] = tab16[i];
    if (tid < 192) {                       // HT prefix partials (8 parts)
        int cv = tid % 24, part = tid / 24;
        float s = 0.f;
        for (int j = part; j < g; j += 8)
            s += (float)HT[(size_t)((b << 8) | j) * 32 + cv];
        phist[part][cv] = s;
    }
    if (tid < 72) {
        int itp = tid / 24, cv = tid % 24;
        h3[itp][cv] = (float)Hsub[(size_t)((bi << 2) | itp) * 24 + cv];
    }
    __syncthreads();
    if (tid < 96) {
        int it = tid / 24, cv = tid % 24;
        float s = 0.f;
#pragma unroll
        for (int p = 0; p < 8; ++p) s += phist[p][cv];
        for (int itp = 0; itp < 3; ++itp) if (itp < it) s += h3[itp][cv];
        scnt4[it][cv] = s;
    }
    __syncthreads();
    if (tid < 64) {                        // layer-0 carries from histograms
#pragma unroll
        for (int it = 0; it < 4; ++it) {
            float s = 0.f;
#pragma unroll
            for (int cv = 0; cv < 24; ++cv)
                s += scnt4[it][cv] * (float)stab[cv * 64 + tid];
            scarr4[it][tid] = s;
        }
    }
    __syncthreads();
    if (tid < 192) {                       // base folds (4 sub-chunks)
        int c = tid >> 6, ff = tid & 63;
        const float* wp = W32 + (size_t)(c * 64 + ff) * 64;
        float4 wr[16];
#pragma unroll
        for (int d4 = 0; d4 < 16; ++d4) wr[d4] = *(const float4*)(wp + d4 * 4);
        float bz = bias[c * 64 + ff];
#pragma unroll
        for (int it = 0; it < 4; ++it) {
            float s0 = 0, s1 = 0, s2 = 0, s3 = 0;
#pragma unroll
            for (int d4 = 0; d4 < 16; ++d4) {
                float4 cv = *(const float4*)&scarr4[it][d4 * 4];
                s0 += cv.x * wr[d4].x; s1 += cv.y * wr[d4].y;
                s2 += cv.z * wr[d4].z; s3 += cv.w * wr[d4].w;
            }
            basearr4[it][tid] = bz + INVN * ((s0 + s1) + (s2 + s3));
        }
    }
    // basearr4 reads first occur after it0's B1+B2 barriers -> safe.

    float TT[4] = {0.f, 0.f, 0.f, 0.f};

    for (int it = 0; it < 4; ++it) {
        int pb = g * 256 + it * 64;
        // layer-0: LUT + serial 16-scan in (f, w) layout
        float y0[3][16];
        {
            int pixbase = pb + w * 16;
#pragma unroll
            for (int p = 0; p < 16; ++p) {
                const int* ep = ex + ((size_t)b * SP + pixbase + p) * 3;
                y0[0][p] = (float)stab[ep[0] * 64 + f];
                y0[1][p] = (float)stab[(8 + ep[1]) * 64 + f];
                y0[2][p] = (float)stab[(16 + ep[2]) * 64 + f];
            }
#pragma unroll
            for (int c = 0; c < 3; ++c)
#pragma unroll
                for (int p = 1; p < 16; ++p) y0[c][p] += y0[c][p - 1];
#pragma unroll
            for (int c = 0; c < 3; ++c) segwt[c][w][f] = y0[c][15];
        }
        __syncthreads();                   // B1
        {
            float off0[3];
#pragma unroll
            for (int c = 0; c < 3; ++c) {
                float o = 0.f;
                for (int g2 = 0; g2 < w; ++g2) o += segwt[c][g2][f];
                off0[c] = o;
            }
#pragma unroll
            for (int p = 0; p < 16; ++p) {
                float S0 = y0[0][p] + off0[0], S1 = y0[1][p] + off0[1], S2 = y0[2][p] + off0[2];
                float P1 = p ? y0[1][p - 1] + off0[1] : off0[1];
                float P2 = p ? y0[2][p - 1] + off0[2] : off0[2];
                int row = w * 16 + p;
                bounce3[0][row * 72 + f] = (_Float16)(S0 + P1 + P2);
                bounce3[1][row * 72 + f] = (_Float16)(S0 + S1 + P2);
                bounce3[2][row * 72 + f] = (_Float16)(S0 + S1 + S2);
            }
        }
        __syncthreads();                   // B2: layer-0 bounce ready
        f32x4 acc[3][4];
#pragma unroll
        for (int c = 0; c < 3; ++c) {
            const half8* bb = (const half8*)&bounce3[c][0];
            half8 a0 = bb[(w * 16 + lm) * 9 + lq];
            half8 a1 = bb[(w * 16 + lm) * 9 + 4 + lq];
#pragma unroll
            for (int nt = 0; nt < 4; ++nt) {
                const half8* bp = (const half8*)(W16 + (size_t)(c * 64 + nt * 16 + lm) * 64);
                f32x4 t = {0.f, 0.f, 0.f, 0.f};
                t = __builtin_amdgcn_mfma_f32_16x16x32_f16(a0, bp[lq],     t, 0, 0, 0);
                t = __builtin_amdgcn_mfma_f32_16x16x32_f16(a1, bp[4 + lq], t, 0, 0, 0);
                acc[c][nt] = t;
            }
        }
        float s[3][4][4], wexcl[3][4];
#pragma unroll
        for (int c = 0; c < 3; ++c)
#pragma unroll
            for (int nt = 0; nt < 4; ++nt) {
                float base = basearr4[it][c * 64 + nt * 16 + lm];
                float run = 0.f;
#pragma unroll
                for (int r = 0; r < 4; ++r) {
                    float yv = fmaxf(base + INVN * acc[c][nt][r], 0.f);
                    run += yv; s[c][nt][r] = run;
                }
                float v = run;
                float t1 = __shfl_up(v, 16); if (lq >= 1) v += t1;
                float t2 = __shfl_up(v, 32); if (lq >= 2) v += t2;
                wexcl[c][nt] = v - run;
                if (lq == 3) segwt[c][w][nt * 16 + lm] = v;
            }
        __syncthreads();                   // B3: wave tops ready
        {
            float off[3][4], tot[3][4];
#pragma unroll
            for (int c = 0; c < 3; ++c)
#pragma unroll
                for (int nt = 0; nt < 4; ++nt) {
                    float o = wexcl[c][nt], ts = 0.f;
#pragma unroll
                    for (int w2 = 0; w2 < 4; ++w2) {
                        float wv = segwt[c][w2][nt * 16 + lm];
                        ts += wv;
                        if (w2 < w) o += wv;
                    }
                    off[c][nt] = o; tot[c][nt] = ts;
                }
            if (w == 0 && lq == 0)
#pragma unroll
                for (int nt = 0; nt < 4; ++nt)
                    A64[(size_t)((bi << 2) | it) * 64 + nt * 16 + lm] =
                        tot[0][nt] + tot[1][nt] + tot[2][nt];
#pragma unroll
            for (int nt = 0; nt < 4; ++nt)
                TT[nt] += tot[0][nt] + tot[1][nt] + tot[2][nt];
#pragma unroll
            for (int nt = 0; nt < 4; ++nt)
#pragma unroll
                for (int r = 0; r < 4; ++r) {
                    float S0 = off[0][nt] + s[0][nt][r];
                    float S1 = off[1][nt] + s[1][nt][r];
                    float S2 = off[2][nt] + s[2][nt][r];
                    float P1 = off[1][nt] + (r ? s[1][nt][r - 1] : 0.f);
                    float P2 = off[2][nt] + (r ? s[2][nt][r - 1] : 0.f);
                    int row = w * 16 + lq * 4 + r;
                    bounce3[0][row * 72 + nt * 16 + lm] = (_Float16)(S0 + P1 + P2);
                    bounce3[1][row * 72 + nt * 16 + lm] = (_Float16)(S0 + S1 + P2);
                    bounce3[2][row * 72 + nt * 16 + lm] = (_Float16)(S0 + S1 + S2);
                }
        }
        __syncthreads();                   // B4: store staging ready
#pragma unroll
        for (int q = 0; q < 6; ++q) {
            int idx = q * 256 + tid;
            int c = idx >> 9, rem = idx & 511;
            int pix = rem >> 3, f8 = rem & 7;
            half8 v = *(const half8*)&bounce3[c][pix * 72 + f8 * 8];
            ((half8*)(Y + ((size_t)(b * 3 + c) * SP + pb + pix) * 64))[f8] = v;
        }
    }
    if (w == 0 && lq == 0)
#pragma unroll
        for (int nt = 0; nt < 4; ++nt)
            T[(size_t)bi * 64 + nt * 16 + lm] = TT[nt];
}

// ---------------- midB: dense layer, Y in-place -----------------------------
__global__ __launch_bounds__(256, 4)
void midB(const _Float16* Yin, _Float16* Yout,
          const float* __restrict__ Tprev, const float* __restrict__ A64prev,
          const _Float16* __restrict__ W16, const float* __restrict__ W32,
          const float* __restrict__ bias,
          float* __restrict__ A64, float* __restrict__ T)
{
    __shared__ __align__(16) _Float16 bounce3[3][64 * 72];
    __shared__ float wtop[3][4][64];
    __shared__ float basearr4[4][192];
    __shared__ float cpart[4][64];
    __shared__ __align__(16) float scarr4[4][64];

    int tid = threadIdx.x, bi = blockIdx.x;
    int b = bi >> 8, g = bi & 255;
    int w = tid >> 6, ln = tid & 63, lm = ln & 15, lq = ln >> 4;

    {
        float s = 0.f;
        for (int j = w; j < g; j += 4)
            s += Tprev[(size_t)((b << 8) | j) * 64 + ln];
        cpart[w][ln] = s;
    }
    __syncthreads();
    if (tid < 64) {
        float cb = cpart[0][tid] + cpart[1][tid] + cpart[2][tid] + cpart[3][tid];
        float a0 = A64prev[(size_t)((bi << 2) | 0) * 64 + tid];
        float a1 = A64prev[(size_t)((bi << 2) | 1) * 64 + tid];
        float a2 = A64prev[(size_t)((bi << 2) | 2) * 64 + tid];
        scarr4[0][tid] = cb;           scarr4[1][tid] = cb + a0;
        scarr4[2][tid] = cb + a0 + a1; scarr4[3][tid] = cb + a0 + a1 + a2;
    }
    __syncthreads();
    if (tid < 192) {
        int c = tid >> 6, ff = tid & 63;
        const float* wp = W32 + (size_t)(c * 64 + ff) * 64;
        float4 wr[16];
#pragma unroll
        for (int d4 = 0; d4 < 16; ++d4) wr[d4] = *(const float4*)(wp + d4 * 4);
        float bz = bias[c * 64 + ff];
#pragma unroll
        for (int it = 0; it < 4; ++it) {
            float s0 = 0, s1 = 0, s2 = 0, s3 = 0;
#pragma unroll
            for (int d4 = 0; d4 < 16; ++d4) {
                float4 cv = *(const float4*)&scarr4[it][d4 * 4];
                s0 += cv.x * wr[d4].x; s1 += cv.y * wr[d4].y;
                s2 += cv.z * wr[d4].z; s3 += cv.w * wr[d4].w;
            }
            basearr4[it][tid] = bz + INVN * ((s0 + s1) + (s2 + s3));
        }
    }
    __syncthreads();                       // basearr ready before it0 scan

    float TT[4] = {0.f, 0.f, 0.f, 0.f};
    for (int it = 0; it < 4; ++it) {
        int pb = g * 256 + it * 64;
        half8 af0[3], af1[3];
#pragma unroll
        for (int c = 0; c < 3; ++c) {
            const half8* ap = (const half8*)(Yin + ((size_t)(b * 3 + c) * SP + pb + w * 16 + lm) * 64);
            af0[c] = ap[lq]; af1[c] = ap[4 + lq];
        }
        f32x4 acc[3][4];
#pragma unroll
        for (int c = 0; c < 3; ++c)
#pragma unroll
            for (int nt = 0; nt < 4; ++nt) {
                const half8* bp = (const half8*)(W16 + (size_t)(c * 64 + nt * 16 + lm) * 64);
                f32x4 t = {0.f, 0.f, 0.f, 0.f};
                t = __builtin_amdgcn_mfma_f32_16x16x32_f16(af0[c], bp[lq],     t, 0, 0, 0);
                t = __builtin_amdgcn_mfma_f32_16x16x32_f16(af1[c], bp[4 + lq], t, 0, 0, 0);
                acc[c][nt] = t;
            }
        float s[3][4][4], wexcl[3][4];
#pragma unroll
        for (int c = 0; c < 3; ++c)
#pragma unroll
            for (int nt = 0; nt < 4; ++nt) {
                float base = basearr4[it][c * 64 + nt * 16 + lm];
                float run = 0.f;
#pragma unroll
                for (int r = 0; r < 4; ++r) {
                    float yv = fmaxf(base + INVN * acc[c][nt][r], 0.f);
                    run += yv; s[c][nt][r] = run;
                }
                float v = run;
                float t1 = __shfl_up(v, 16); if (lq >= 1) v += t1;
                float t2 = __shfl_up(v, 32); if (lq >= 2) v += t2;
                wexcl[c][nt] = v - run;
                if (lq == 3) wtop[c][w][nt * 16 + lm] = v;
            }
        __syncthreads();                   // B1
        {
            float off[3][4], tot[3][4];
#pragma unroll
            for (int c = 0; c < 3; ++c)
#pragma unroll
                for (int nt = 0; nt < 4; ++nt) {
                    float o = wexcl[c][nt], ts = 0.f;
#pragma unroll
                    for (int w2 = 0; w2 < 4; ++w2) {
                        float wv = wtop[c][w2][nt * 16 + lm];
                        ts += wv;
                        if (w2 < w) o += wv;
                    }
                    off[c][nt] = o; tot[c][nt] = ts;
                }
            if (w == 0 && lq == 0)
#pragma unroll
                for (int nt = 0; nt < 4; ++nt)
                    A64[(size_t)((bi << 2) | it) * 64 + nt * 16 + lm] =
                        tot[0][nt] + tot[1][nt] + tot[2][nt];
#pragma unroll
            for (int nt = 0; nt < 4; ++nt)
                TT[nt] += tot[0][nt] + tot[1][nt] + tot[2][nt];
#pragma unroll
            for (int nt = 0; nt < 4; ++nt)
#pragma unroll
                for (int r = 0; r < 4; ++r) {
                    float S0 = off[0][nt] + s[0][nt][r];
                    float S1 = off[1][nt] + s[1][nt][r];
                    float S2 = off[2][nt] + s[2][nt][r];
                    float P1 = off[1][nt] + (r ? s[1][nt][r - 1] : 0.f);
                    float P2 = off[2][nt] + (r ? s[2][nt][r - 1] : 0.f);
                    int row = w * 16 + lq * 4 + r;
                    bounce3[0][row * 72 + nt * 16 + lm] = (_Float16)(S0 + P1 + P2);
                    bounce3[1][row * 72 + nt * 16 + lm] = (_Float16)(S0 + S1 + P2);
                    bounce3[2][row * 72 + nt * 16 + lm] = (_Float16)(S0 + S1 + S2);
                }
        }
        __syncthreads();                   // B2
#pragma unroll
        for (int q = 0; q < 6; ++q) {
            int idx = q * 256 + tid;
            int c = idx >> 9, rem = idx & 511;
            int pix = rem >> 3, f8 = rem & 7;
            half8 v = *(const half8*)&bounce3[c][pix * 72 + f8 * 8];
            ((half8*)(Yout + ((size_t)(b * 3 + c) * SP + pb + pix) * 64))[f8] = v;
        }
    }
    if (w == 0 && lq == 0)
#pragma unroll
        for (int nt = 0; nt < 4; ++nt)
            T[(size_t)bi * 64 + nt * 16 + lm] = TT[nt];
}

// ---------------- midC: dense3 + final dense -> out_partial -----------------
__global__ __launch_bounds__(256, 4)
void midC(const _Float16* __restrict__ Yin,
          const float* __restrict__ Tprev, const float* __restrict__ A64prev,
          const _Float16* __restrict__ W16, const float* __restrict__ W32,
          const float* __restrict__ bias,
          const _Float16* __restrict__ Wf16, const float* __restrict__ bfin,
          float* __restrict__ out, float* __restrict__ A64, float* __restrict__ T)
{
    __shared__ __align__(16) _Float16 bounce3[3][64 * 72];
    __shared__ float wtop[3][4][64];
    __shared__ float basearr4[4][192];
    __shared__ float cpart[4][64];
    __shared__ __align__(16) float scarr4[4][64];
    __shared__ _Float16 swf[1536];
    __shared__ float sbf[24];

    int tid = threadIdx.x, bi = blockIdx.x;
    int b = bi >> 8, g = bi & 255;
    int w = tid >> 6, ln = tid & 63, lm = ln & 15, lq = ln >> 4;

    for (int i = tid; i < 1536; i += 256) swf[i] = Wf16[i];
    if (tid < 24) sbf[tid] = bfin[tid];
    {
        float s = 0.f;
        for (int j = w; j < g; j += 4)
            s += Tprev[(size_t)((b << 8) | j) * 64 + ln];
        cpart[w][ln] = s;
    }
    __syncthreads();
    if (tid < 64) {
        float cb = cpart[0][tid] + cpart[1][tid] + cpart[2][tid] + cpart[3][tid];
        float a0 = A64prev[(size_t)((bi << 2) | 0) * 64 + tid];
        float a1 = A64prev[(size_t)((bi << 2) | 1) * 64 + tid];
        float a2 = A64prev[(size_t)((bi << 2) | 2) * 64 + tid];
        scarr4[0][tid] = cb;           scarr4[1][tid] = cb + a0;
        scarr4[2][tid] = cb + a0 + a1; scarr4[3][tid] = cb + a0 + a1 + a2;
    }
    __syncthreads();
    if (tid < 192) {
        int c = tid >> 6, ff = tid & 63;
        const float* wp = W32 + (size_t)(c * 64 + ff) * 64;
        float4 wr[16];
#pragma unroll
        for (int d4 = 0; d4 < 16; ++d4) wr[d4] = *(const float4*)(wp + d4 * 4);
        float bz = bias[c * 64 + ff];
#pragma unroll
        for (int it = 0; it < 4; ++it) {
            float s0 = 0, s1 = 0, s2 = 0, s3 = 0;
#pragma unroll
            for (int d4 = 0; d4 < 16; ++d4) {
                float4 cv = *(const float4*)&scarr4[it][d4 * 4];
                s0 += cv.x * wr[d4].x; s1 += cv.y * wr[d4].y;
                s2 += cv.z * wr[d4].z; s3 += cv.w * wr[d4].w;
            }
            basearr4[it][tid] = bz + INVN * ((s0 + s1) + (s2 + s3));
        }
    }
    __syncthreads();

    float TT[4] = {0.f, 0.f, 0.f, 0.f};
    for (int it = 0; it < 4; ++it) {
        int pb = g * 256 + it * 64;
        half8 af0[3], af1[3];
#pragma unroll
        for (int c = 0; c < 3; ++c) {
            const half8* ap = (const half8*)(Yin + ((size_t)(b * 3 + c) * SP + pb + w * 16 + lm) * 64);
            af0[c] = ap[lq]; af1[c] = ap[4 + lq];
        }
        f32x4 acc[3][4];
#pragma unroll
        for (int c = 0; c < 3; ++c)
#pragma unroll
            for (int nt = 0; nt < 4; ++nt) {
                const half8* bp = (const half8*)(W16 + (size_t)(c * 64 + nt * 16 + lm) * 64);
                f32x4 t = {0.f, 0.f, 0.f, 0.f};
                t = __builtin_amdgcn_mfma_f32_16x16x32_f16(af0[c], bp[lq],     t, 0, 0, 0);
                t = __builtin_amdgcn_mfma_f32_16x16x32_f16(af1[c], bp[4 + lq], t, 0, 0, 0);
                acc[c][nt] = t;
            }
        float s[3][4][4], wexcl[3][4];
#pragma unroll
        for (int c = 0; c < 3; ++c)
#pragma unroll
            for (int nt = 0; nt < 4; ++nt) {
                float base = basearr4[it][c * 64 + nt * 16 + lm];
                float run = 0.f;
#pragma unroll
                for (int r = 0; r < 4; ++r) {
                    float yv = fmaxf(base + INVN * acc[c][nt][r], 0.f);
                    run += yv; s[c][nt][r] = run;
                }
                float v = run;
                float t1 = __shfl_up(v, 16); if (lq >= 1) v += t1;
                float t2 = __shfl_up(v, 32); if (lq >= 2) v += t2;
                wexcl[c][nt] = v - run;
                if (lq == 3) wtop[c][w][nt * 16 + lm] = v;
            }
        __syncthreads();                   // B1
        {
            float off[3][4], tot[3][4];
#pragma unroll
            for (int c = 0; c < 3; ++c)
#pragma unroll
                for (int nt = 0; nt < 4; ++nt) {
                    float o = wexcl[c][nt], ts = 0.f;
#pragma unroll
                    for (int w2 = 0; w2 < 4; ++w2) {
                        float wv = wtop[c][w2][nt * 16 + lm];
                        ts += wv;
                        if (w2 < w) o += wv;
                    }
                    off[c][nt] = o; tot[c][nt] = ts;
                }
            if (w == 0 && lq == 0)
#pragma unroll
                for (int nt = 0; nt < 4; ++nt)
                    A64[(size_t)((bi << 2) | it) * 64 + nt * 16 + lm] =
                        tot[0][nt] + tot[1][nt] + tot[2][nt];
#pragma unroll
            for (int nt = 0; nt < 4; ++nt)
                TT[nt] += tot[0][nt] + tot[1][nt] + tot[2][nt];
#pragma unroll
            for (int nt = 0; nt < 4; ++nt)
#pragma unroll
                for (int r = 0; r < 4; ++r) {
                    float S0 = off[0][nt] + s[0][nt][r];
                    float S1 = off[1][nt] + s[1][nt][r];
                    float S2 = off[2][nt] + s[2][nt][r];
                    float P1 = off[1][nt] + (r ? s[1][nt][r - 1] : 0.f);
                    float P2 = off[2][nt] + (r ? s[2][nt][r - 1] : 0.f);
                    int row = w * 16 + lq * 4 + r;
                    bounce3[0][row * 72 + nt * 16 + lm] = (_Float16)(S0 + P1 + P2);
                    bounce3[1][row * 72 + nt * 16 + lm] = (_Float16)(S0 + S1 + P2);
                    bounce3[2][row * 72 + nt * 16 + lm] = (_Float16)(S0 + S1 + S2);
                }
        }
        __syncthreads();                   // B2: layer-3 local cumsum staged
        // final dense on local part: 192 threads = 64 pix x 3 ch
        float sk[8];
        int pixl = tid & 63, cch = tid >> 6;
        if (tid < 192) {
#pragma unroll
            for (int k = 0; k < 8; ++k) sk[k] = 0.f;
            const half8* rp = (const half8*)&bounce3[cch][pixl * 72];
#pragma unroll
            for (int j8 = 0; j8 < 8; ++j8) {
                half8 h = rp[j8];
#pragma unroll
                for (int e = 0; e < 8; ++e) {
                    float xv = (float)h[e];
                    int d = j8 * 8 + e;
#pragma unroll
                    for (int k = 0; k < 8; ++k)
                        sk[k] += xv * (float)swf[(cch * 8 + k) * 64 + d];
                }
            }
        }
        __syncthreads();                   // B3: bounce reads done
        float* outst = (float*)&bounce3[0][0];
        if (tid < 192)
#pragma unroll
            for (int k = 0; k < 8; ++k)
                outst[pixl * 24 + cch * 8 + k] = sbf[cch * 8 + k] + INVN * sk[k];
        __syncthreads();                   // B4
        {
            float4* obase = (float4*)(out + ((size_t)b * SS + (size_t)pb * 3) * 8);
#pragma unroll
            for (int q = 0; q < 2; ++q) {
                int idx = q * 256 + tid;
                if (idx < 384) obase[idx] = ((float4*)outst)[idx];
            }
        }
    }
    if (w == 0 && lq == 0)
#pragma unroll
        for (int nt = 0; nt < 4; ++nt)
            T[(size_t)bi * 64 + nt * 16 + lm] = TT[nt];
}

// ---------------- fix: out += INVN * Wf . carry3 ----------------------------
__global__ __launch_bounds__(256)
void fixk(const float* __restrict__ T3, const float* __restrict__ A64_3,
          const _Float16* __restrict__ Wf16, float* __restrict__ out)
{
    __shared__ float cpart[4][64];
    __shared__ __align__(16) float scar4[4][64];
    __shared__ _Float16 swf[1536];
    __shared__ float vfix[4][24];
    int tid = threadIdx.x, bi = blockIdx.x;
    int b = bi >> 8, g = bi & 255;
    int w = tid >> 6, ln = tid & 63;

    for (int i = tid; i < 1536; i += 256) swf[i] = Wf16[i];
    {
        float s = 0.f;
        for (int j = w; j < g; j += 4)
            s += T3[(size_t)((b << 8) | j) * 64 + ln];
        cpart[w][ln] = s;
    }
    __syncthreads();
    if (tid < 64) {
        float cb = cpart[0][tid] + cpart[1][tid] + cpart[2][tid] + cpart[3][tid];
        float a0 = A64_3[(size_t)((bi << 2) | 0) * 64 + tid];
        float a1 = A64_3[(size_t)((bi << 2) | 1) * 64 + tid];
        float a2 = A64_3[(size_t)((bi << 2) | 2) * 64 + tid];
        scar4[0][tid] = cb;           scar4[1][tid] = cb + a0;
        scar4[2][tid] = cb + a0 + a1; scar4[3][tid] = cb + a0 + a1 + a2;
    }
    __syncthreads();
    if (tid < 96) {
        int it = tid / 24, ck = tid % 24;
        float s = 0.f;
#pragma unroll 8
        for (int d = 0; d < 64; ++d)
            s += scar4[it][d] * (float)swf[ck * 64 + d];
        vfix[it][ck] = INVN * s;
    }
    __syncthreads();
    float* obase = out + ((size_t)b * SS + (size_t)g * 768) * 8;
#pragma unroll
    for (int q = 0; q < 6; ++q) {
        int idx = q * 256 + tid;           // float4 index, 0..1535
        int lp = idx >> 1, hf = idx & 1;
        int pixl = lp / 3;
        int c = lp - pixl * 3;
        int it = pixl >> 6;
        float4 v = *((float4*)obase + idx);
        v.x += vfix[it][c * 8 + hf * 4 + 0];
        v.y += vfix[it][c * 8 + hf * 4 + 1];
        v.z += vfix[it][c * 8 + hf * 4 + 2];
        v.w += vfix[it][c * 8 + hf * 4 + 3];
        *((float4*)obase + idx) = v;
    }
}

// ---------------- host -------------------------------------------------------
extern "C" void kernel_launch(void* const* d_in, const int* in_sizes, int n_in,
                              void* d_out, int out_size, void* d_ws, size_t ws_size,
                              hipStream_t stream)
{
    const int*   ex   = (const int*)d_in[0];
    const float* W0   = (const float*)d_in[1];
    const float* b0   = (const float*)d_in[2];
    const float* Wr   = (const float*)d_in[3];
    const float* br   = (const float*)d_in[4];
    const float* Wfin = (const float*)d_in[5];
    const float* bfin = (const float*)d_in[6];
    float* out = (float*)d_out;

    char* ws = (char*)d_ws;
    size_t off = 0;
    _Float16* Y = (_Float16*)(ws + off); off += (size_t)BB * 3 * SP * 64 * 2;  // 100.7 MB
    float* T1    = (float*)(ws + off); off += 1024 * 64 * 4;
    float* T2    = (float*)(ws + off); off += 1024 * 64 * 4;
    float* T3    = (float*)(ws + off); off += 1024 * 64 * 4;
    float* A64_1 = (float*)(ws + off); off += 4096 * 64 * 4;
    float* A64_2 = (float*)(ws + off); off += 4096 * 64 * 4;
    float* A64_3 = (float*)(ws + off); off += 4096 * 64 * 4;
    int*   Hsub  = (int*)(ws + off);   off += 4096 * 24 * 4;
    int*   HT    = (int*)(ws + off);   off += 1024 * 32 * 4;
    float* Wt32  = (float*)(ws + off); off += 36864 * 4;
    _Float16* Wt16  = (_Float16*)(ws + off); off += 36864 * 2;
    _Float16* Wf16  = (_Float16*)(ws + off); off += 1536 * 2;
    _Float16* tab16 = (_Float16*)(ws + off); off += 1536 * 2;

    prep_hist<<<1024, 256, 0, stream>>>(ex, W0, b0, Wr, Wfin,
                                        Wt32, Wt16, Wf16, tab16, Hsub, HT);
    midA<<<1024, 256, 0, stream>>>(ex, Hsub, HT, tab16,
                                   Wt16, Wt32, br, Y, A64_1, T1);
    midB<<<1024, 256, 0, stream>>>(Y, Y, T1, A64_1,
                                   Wt16 + 12288, Wt32 + 12288, br + 192, A64_2, T2);
    midC<<<1024, 256, 0, stream>>>(Y, T2, A64_2,
                                   Wt16 + 24576, Wt32 + 24576, br + 384,
                                   Wf16, bfin, out, A64_3, T3);
    fixk<<<1024, 256, 0, stream>>>(T3, A64_3, Wf16, out);
}